// Round 11
// baseline (224.623 us; speedup 1.0000x reference)
//
#include <hip/hip_runtime.h>
#include <math.h>

// Cone-beam forward projection (TIGRE Ax analogue).
// Volume: [B=2, NZ=96, NY=96, NX=96] f32, ZYX layout (x fastest).
// Output: [B=2, A=48, NV=96, NU=96] f32.
//
// R11: R10 (batch-interleaved float2, 4x dwordx4 gathers/sample-pair) plus an
// ORDER-PRESERVING DEPTH-2 SOFTWARE PIPELINE: the next sample's 4 loads are
// issued before the current sample's values are consumed, so 8 loads are in
// flight per wave and the per-iteration exposed L2 latency (~200 cy, the
// measured invariant ~245 cy/iter across R4/R7/R9/R10) is halved.
// Branch-free body (clamp for addressing + select for accumulate), per-lane
// k-range. Per-k arithmetic and accumulation order are IDENTICAL to R10 ->
// bit-identical output.
//
// CORRECTNESS-CRITICAL: reference integrand is DISCONTINUOUS at cube faces.
// Position path replicates the reference's f32 op sequence exactly:
// contract(off), per-sample src + d*t, IEEE sqrt+div, f64-rounded trig.

#define NZg 96
#define NYg 96
#define NXg 96
#define NVg 96
#define NUg 96
#define NAg 48
#define NSg 96
#define NBg 2
#define NVOX (NZg * NYg * NXg)          // 884736 voxels per batch
#define NRAY1 (NAg * NVg * NUg)         // 442368 rays per batch
#define PLANE (NYg * NXg)               // 9216 float2 elements per z-plane

typedef float v4f __attribute__((ext_vector_type(4)));

// ---------------- staging: interleave the two batches ---------------------
__global__ __launch_bounds__(256) void pack_b2(
    const float* __restrict__ vol, float2* __restrict__ q) {
    const int i = blockIdx.x * blockDim.x + threadIdx.x;  // [z][y][x]
    float2 p;
    p.x = vol[i];
    p.y = vol[i + NVOX];
    q[i] = p;
}

// ---------------- shared geometry (b-independent) -------------------------
__device__ __forceinline__ void ray_setup(
    int ridx, float& srcx, float& srcy, float& dx, float& dy, float& dz,
    int& k0, int& k1) {
#pragma clang fp contract(off)
    const int u   = ridx % NUg;
    int tmp       = ridx / NUg;
    const int v   = tmp % NVg;
    const int a   = tmp / NVg;          // < 48, uniform per block

    // theta = a * (f32(2*pi) / 48)   [jax linspace f32 semantics]
    const float dtheta = 6.2831855f / 48.0f;
    const float theta  = (float)a * dtheta;
    const float c = (float)cos((double)theta);
    const float s = (float)sin((double)theta);

    srcx = 500.0f * c;
    srcy = 500.0f * s;
    const float uu = ((float)u - 47.5f) * 2.0f;
    const float vv = ((float)v - 47.5f) * 2.0f;
    const float pixx = (-500.0f * c) + uu * (-s);
    const float pixy = (-500.0f * s) + uu * c;
    const float pixz = vv;

    const float dx0 = pixx - srcx;
    const float dy0 = pixy - srcy;
    const float dz0 = pixz;
    const float nrm = sqrtf((dx0 * dx0 + dy0 * dy0) + dz0 * dz0);
    dx = dx0 / nrm;
    dy = dy0 / nrm;
    dz = dz0 / nrm;

    const float stepf = (float)1.7320508075688773;   // f32(2R/96)
    const float t0f   = (float)416.8615612366939;    // f32(DSO-R)

    // conservative AABB clip (skip-only; in-loop test is authoritative)
    const float LO = -47.51f, HI = 47.51f;
    float tlo = -1e30f, thi = 1e30f;
    {
        const float o3[3] = {srcx, srcy, 0.0f};
        const float d3[3] = {dx, dy, dz};
        bool empty = false;
        #pragma unroll
        for (int ax = 0; ax < 3; ++ax) {
            const float oo = o3[ax], dd = d3[ax];
            if (fabsf(dd) > 1e-8f) {
                const float inv = 1.0f / dd;
                const float ta = (LO - oo) * inv;
                const float tb = (HI - oo) * inv;
                tlo = fmaxf(tlo, fminf(ta, tb));
                thi = fminf(thi, fmaxf(ta, tb));
            } else if (oo < LO || oo > HI) {
                empty = true;
            }
        }
        if (empty) { tlo = 1.0f; thi = 0.0f; }
    }
    if (thi >= tlo) {
        k0 = (int)floorf((tlo - t0f) / stepf) - 2;
        k1 = (int)ceilf((thi - t0f) / stepf) + 2;
        k0 = max(k0, 0);
        k1 = min(k1, NSg - 1);
    } else {
        k0 = 1; k1 = 0;
    }
}

// one pipeline stage: per-k sample state + its 4 in-flight row loads
struct Stage {
    v4f r00, r01, r10, r11;
    float fx, fy, fz;
    bool valid;
};

__device__ __forceinline__ Stage make_stage(
    const float2* __restrict__ q, int k,
    float srcx, float srcy, float dx, float dy, float dz) {
#pragma clang fp contract(off)
    const float stepf = (float)1.7320508075688773;
    const float t0f   = (float)416.8615612366939;
    Stage st;
    const float tk = t0f + ((float)k + 0.5f) * stepf;
    const float ix = (srcx + dx * tk) + 47.5f;
    const float iy = (srcy + dy * tk) + 47.5f;
    const float iz = (dz * tk) + 47.5f;
    st.valid = (ix >= 0.0f) & (ix <= 95.0f) &
               (iy >= 0.0f) & (iy <= 95.0f) &
               (iz >= 0.0f) & (iz <= 95.0f);
    // clamp for addressing only; when valid, clamped == original
    const float ixc = fminf(fmaxf(ix, 0.0f), 95.0f);
    const float iyc = fminf(fmaxf(iy, 0.0f), 95.0f);
    const float izc = fminf(fmaxf(iz, 0.0f), 95.0f);
    const int x0 = min((int)ixc, NXg - 2);
    const int y0 = min((int)iyc, NYg - 2);
    const int z0 = min((int)izc, NZg - 2);
    st.fx = ixc - (float)x0;
    st.fy = iyc - (float)y0;
    st.fz = izc - (float)z0;
    const int base = (z0 * NYg + y0) * NXg + x0;
    st.r00 = *(const v4f*)(q + base);                // (y0,z0): b0@x0,b1@x0,b0@x1,b1@x1
    st.r01 = *(const v4f*)(q + base + NXg);          // (y1,z0)
    st.r10 = *(const v4f*)(q + base + PLANE);        // (y0,z1)
    st.r11 = *(const v4f*)(q + base + PLANE + NXg);  // (y1,z1)
    return st;
}

__device__ __forceinline__ void consume_stage(
    const Stage& st, float& acc0, float& acc1) {
#pragma clang fp contract(off)
    const float fx = st.fx, fy = st.fy, fz = st.fz;
    // batch 0 (op-order identical to R2/R7/R10)
    {
        const float c00 = st.r00.x + fx * (st.r00.z - st.r00.x);
        const float c01 = st.r01.x + fx * (st.r01.z - st.r01.x);
        const float c10 = st.r10.x + fx * (st.r10.z - st.r10.x);
        const float c11 = st.r11.x + fx * (st.r11.z - st.r11.x);
        const float c0  = c00 + fy * (c01 - c00);
        const float c1  = c10 + fy * (c11 - c10);
        const float tri = c0 + fz * (c1 - c0);
        acc0 += st.valid ? tri : 0.0f;
    }
    // batch 1
    {
        const float c00 = st.r00.y + fx * (st.r00.w - st.r00.y);
        const float c01 = st.r01.y + fx * (st.r01.w - st.r01.y);
        const float c10 = st.r10.y + fx * (st.r10.w - st.r10.y);
        const float c11 = st.r11.y + fx * (st.r11.w - st.r11.y);
        const float c0  = c00 + fy * (c01 - c00);
        const float c1  = c10 + fy * (c11 - c10);
        const float tri = c0 + fz * (c1 - c0);
        acc1 += st.valid ? tri : 0.0f;
    }
}

// ---------------- main: depth-2 pipelined projector -----------------------
__global__ __launch_bounds__(256) void coneproj_pipe(
    const float2* __restrict__ q, float* __restrict__ out) {
#pragma clang fp contract(off)
    const int ridx = blockIdx.x * blockDim.x + threadIdx.x;  // (a*96+v)*96+u
    float srcx, srcy, dx, dy, dz;
    int k0, k1;
    ray_setup(ridx, srcx, srcy, dx, dy, dz, k0, k1);

    const float stepf = (float)1.7320508075688773;

    float acc0 = 0.0f, acc1 = 0.0f;
    if (k0 <= k1) {
        Stage cur = make_stage(q, k0, srcx, srcy, dx, dy, dz);
        for (int k = k0; k <= k1; ++k) {
            const int kn = (k < k1) ? (k + 1) : k1;  // last iter: dummy reload
            Stage nxt = make_stage(q, kn, srcx, srcy, dx, dy, dz);
            consume_stage(cur, acc0, acc1);
            cur = nxt;
        }
    }
    out[ridx]         = acc0 * stepf;
    out[ridx + NRAY1] = acc1 * stepf;
}

// ---------------- fallback: direct 8-gather projector (R2) ----------------
__global__ __launch_bounds__(256) void coneproj_direct(
    const float* __restrict__ vol, float* __restrict__ out) {
#pragma clang fp contract(off)
    const int gidx = blockIdx.x * blockDim.x + threadIdx.x;  // includes b
    const int ridx = gidx % NRAY1;
    const int b    = gidx / NRAY1;
    float srcx, srcy, dx, dy, dz;
    int k0, k1;
    ray_setup(ridx, srcx, srcy, dx, dy, dz, k0, k1);

    const float stepf = (float)1.7320508075688773;
    const float t0f   = (float)416.8615612366939;

    const float* __restrict__ volb = vol + (size_t)b * NVOX;

    float acc = 0.0f;
    for (int k = k0; k <= k1; ++k) {
        const float tk = t0f + ((float)k + 0.5f) * stepf;
        const float ix = (srcx + dx * tk) + 47.5f;
        const float iy = (srcy + dy * tk) + 47.5f;
        const float iz = (dz * tk) + 47.5f;
        if (ix >= 0.0f && ix <= 95.0f &&
            iy >= 0.0f && iy <= 95.0f &&
            iz >= 0.0f && iz <= 95.0f) {
            const int x0 = min((int)ix, NXg - 2);
            const int y0 = min((int)iy, NYg - 2);
            const int z0 = min((int)iz, NZg - 2);
            const float fx = ix - (float)x0;
            const float fy = iy - (float)y0;
            const float fz = iz - (float)z0;
            const float* p = volb + ((z0 * NYg + y0) * NXg + x0);
            const float v000 = p[0];
            const float v001 = p[1];
            const float v010 = p[NXg];
            const float v011 = p[NXg + 1];
            const float v100 = p[NYg * NXg];
            const float v101 = p[NYg * NXg + 1];
            const float v110 = p[NYg * NXg + NXg];
            const float v111 = p[NYg * NXg + NXg + 1];
            const float c00 = v000 + fx * (v001 - v000);
            const float c01 = v010 + fx * (v011 - v010);
            const float c10 = v100 + fx * (v101 - v100);
            const float c11 = v110 + fx * (v111 - v110);
            const float c0  = c00 + fy * (c01 - c00);
            const float c1  = c10 + fy * (c11 - c10);
            acc += c0 + fz * (c1 - c0);
        }
    }
    out[gidx] = acc * stepf;
}

extern "C" void kernel_launch(void* const* d_in, const int* in_sizes, int n_in,
                              void* d_out, int out_size, void* d_ws, size_t ws_size,
                              hipStream_t stream) {
    const float* vol = (const float*)d_in[0];
    float* out = (float*)d_out;
    const size_t needed = (size_t)NVOX * sizeof(float2);  // ~7.08 MB
    if (ws_size >= needed) {
        float2* q = (float2*)d_ws;
        pack_b2<<<NVOX / 256, 256, 0, stream>>>(vol, q);
        coneproj_pipe<<<NRAY1 / 256, 256, 0, stream>>>(q, out);
    } else {
        coneproj_direct<<<(NBg * NRAY1) / 256, 256, 0, stream>>>(vol, out);
    }
}

// Round 12
// 217.854 us; speedup vs baseline: 1.0311x; 1.0311x over previous
//
#include <hip/hip_runtime.h>
#include <math.h>

// Cone-beam forward projection (TIGRE Ax analogue).
// Volume: [B=2, NZ=96, NY=96, NX=96] f32, ZYX layout (x fastest).
// Output: [B=2, A=48, NV=96, NU=96] f32.
//
// R12: K-SPLIT ACROSS 2 THREADS PER RAY (tid = ray*2 + half). Surviving
// cost model after R2..R11: ~244 cy exposed L2-hit latency per wave-iter,
// covered only by wave TLP (~4 waves/SIMD at 50% occupancy -> 61 cy/iter).
// Doubling waves + halving per-wave chain length halves wall time. Halves
// are combined with one __shfl_xor; re-association error ~1e-4 is far below
// the 1.51 threshold (the 1.50 absmax is validity-flip noise, fixed by the
// position arithmetic, which is UNCHANGED).
// Gathers stay R10-style: 4x global_load_dwordx4 on the batch-interleaved
// float2 volume (7.1 MB, L2-resident; FETCH must stay ~26 MB).
//
// CORRECTNESS-CRITICAL: reference integrand is DISCONTINUOUS at cube faces.
// Position path replicates the reference's f32 op sequence exactly:
// contract(off), per-sample src + d*t, IEEE sqrt+div, f64-rounded trig.

#define NZg 96
#define NYg 96
#define NXg 96
#define NVg 96
#define NUg 96
#define NAg 48
#define NSg 96
#define NBg 2
#define NVOX (NZg * NYg * NXg)          // 884736 voxels per batch
#define NRAY1 (NAg * NVg * NUg)         // 442368 rays per batch
#define PLANE (NYg * NXg)               // 9216 float2 elements per z-plane

typedef float v4f __attribute__((ext_vector_type(4)));

// ---------------- staging: interleave the two batches ---------------------
__global__ __launch_bounds__(256) void pack_b2(
    const float* __restrict__ vol, float2* __restrict__ q) {
    const int i = blockIdx.x * blockDim.x + threadIdx.x;  // [z][y][x]
    float2 p;
    p.x = vol[i];
    p.y = vol[i + NVOX];
    q[i] = p;
}

// ---------------- shared geometry (b-independent) -------------------------
__device__ __forceinline__ void ray_setup(
    int ridx, float& srcx, float& srcy, float& dx, float& dy, float& dz,
    int& k0, int& k1) {
#pragma clang fp contract(off)
    const int u   = ridx % NUg;
    int tmp       = ridx / NUg;
    const int v   = tmp % NVg;
    const int a   = tmp / NVg;          // < 48

    // theta = a * (f32(2*pi) / 48)   [jax linspace f32 semantics]
    const float dtheta = 6.2831855f / 48.0f;
    const float theta  = (float)a * dtheta;
    const float c = (float)cos((double)theta);
    const float s = (float)sin((double)theta);

    srcx = 500.0f * c;
    srcy = 500.0f * s;
    const float uu = ((float)u - 47.5f) * 2.0f;
    const float vv = ((float)v - 47.5f) * 2.0f;
    const float pixx = (-500.0f * c) + uu * (-s);
    const float pixy = (-500.0f * s) + uu * c;
    const float pixz = vv;

    const float dx0 = pixx - srcx;
    const float dy0 = pixy - srcy;
    const float dz0 = pixz;
    const float nrm = sqrtf((dx0 * dx0 + dy0 * dy0) + dz0 * dz0);
    dx = dx0 / nrm;
    dy = dy0 / nrm;
    dz = dz0 / nrm;

    const float stepf = (float)1.7320508075688773;   // f32(2R/96)
    const float t0f   = (float)416.8615612366939;    // f32(DSO-R)

    // conservative AABB clip (skip-only; in-loop test is authoritative)
    const float LO = -47.51f, HI = 47.51f;
    float tlo = -1e30f, thi = 1e30f;
    {
        const float o3[3] = {srcx, srcy, 0.0f};
        const float d3[3] = {dx, dy, dz};
        bool empty = false;
        #pragma unroll
        for (int ax = 0; ax < 3; ++ax) {
            const float oo = o3[ax], dd = d3[ax];
            if (fabsf(dd) > 1e-8f) {
                const float inv = 1.0f / dd;
                const float ta = (LO - oo) * inv;
                const float tb = (HI - oo) * inv;
                tlo = fmaxf(tlo, fminf(ta, tb));
                thi = fminf(thi, fmaxf(ta, tb));
            } else if (oo < LO || oo > HI) {
                empty = true;
            }
        }
        if (empty) { tlo = 1.0f; thi = 0.0f; }
    }
    if (thi >= tlo) {
        k0 = (int)floorf((tlo - t0f) / stepf) - 2;
        k1 = (int)ceilf((thi - t0f) / stepf) + 2;
        k0 = max(k0, 0);
        k1 = min(k1, NSg - 1);
    } else {
        k0 = 1; k1 = 0;
    }
}

// ---------------- main: 2 threads per ray (k-split) -----------------------
__global__ __launch_bounds__(256) void coneproj_ksplit(
    const float2* __restrict__ q, float* __restrict__ out) {
#pragma clang fp contract(off)
    const int tid  = blockIdx.x * blockDim.x + threadIdx.x;
    const int half = tid & 1;
    const int ridx = tid >> 1;           // (a*96+v)*96+u
    float srcx, srcy, dx, dy, dz;
    int k0, k1;
    ray_setup(ridx, srcx, srcy, dx, dy, dz, k0, k1);

    const float stepf = (float)1.7320508075688773;
    const float t0f   = (float)416.8615612366939;

    // split [k0, k1] into [k0, kmid-1] (half 0) and [kmid, k1] (half 1)
    const int len  = k1 - k0 + 1;                 // may be <= 0 (empty)
    const int kmid = k0 + ((len + 1) >> 1);
    const int ka   = half ? kmid : k0;
    const int kb   = half ? k1 : (kmid - 1);

    float acc0 = 0.0f, acc1 = 0.0f;
    for (int k = ka; k <= kb; ++k) {
        const float tk = t0f + ((float)k + 0.5f) * stepf;
        const float ix = (srcx + dx * tk) + 47.5f;
        const float iy = (srcy + dy * tk) + 47.5f;
        const float iz = (dz * tk) + 47.5f;
        if (ix >= 0.0f && ix <= 95.0f &&
            iy >= 0.0f && iy <= 95.0f &&
            iz >= 0.0f && iz <= 95.0f) {
            const int x0 = min((int)ix, NXg - 2);
            const int y0 = min((int)iy, NYg - 2);
            const int z0 = min((int)iz, NZg - 2);
            const float fx = ix - (float)x0;
            const float fy = iy - (float)y0;
            const float fz = iz - (float)z0;
            const int base = (z0 * NYg + y0) * NXg + x0;
            // 4 x 16B gathers: each row-load = (b0@x0, b1@x0, b0@x1, b1@x1)
            const v4f r00 = *(const v4f*)(q + base);                // (y0,z0)
            const v4f r01 = *(const v4f*)(q + base + NXg);          // (y1,z0)
            const v4f r10 = *(const v4f*)(q + base + PLANE);        // (y0,z1)
            const v4f r11 = *(const v4f*)(q + base + PLANE + NXg);  // (y1,z1)
            // batch 0 (per-k op-order identical to R2/R7/R10)
            {
                const float c00 = r00.x + fx * (r00.z - r00.x);
                const float c01 = r01.x + fx * (r01.z - r01.x);
                const float c10 = r10.x + fx * (r10.z - r10.x);
                const float c11 = r11.x + fx * (r11.z - r11.x);
                const float c0  = c00 + fy * (c01 - c00);
                const float c1  = c10 + fy * (c11 - c10);
                acc0 += c0 + fz * (c1 - c0);
            }
            // batch 1
            {
                const float c00 = r00.y + fx * (r00.w - r00.y);
                const float c01 = r01.y + fx * (r01.w - r01.y);
                const float c10 = r10.y + fx * (r10.w - r10.y);
                const float c11 = r11.y + fx * (r11.w - r11.y);
                const float c0  = c00 + fy * (c01 - c00);
                const float c1  = c10 + fy * (c11 - c10);
                acc1 += c0 + fz * (c1 - c0);
            }
        }
    }

    // combine halves: (first half) + (second half), computed on even lane
    const float o0 = __shfl_xor(acc0, 1, 64);
    const float o1 = __shfl_xor(acc1, 1, 64);
    if (half == 0) {
        out[ridx]         = (acc0 + o0) * stepf;
        out[ridx + NRAY1] = (acc1 + o1) * stepf;
    }
}

// ---------------- fallback: direct 8-gather projector (R2) ----------------
__global__ __launch_bounds__(256) void coneproj_direct(
    const float* __restrict__ vol, float* __restrict__ out) {
#pragma clang fp contract(off)
    const int gidx = blockIdx.x * blockDim.x + threadIdx.x;  // includes b
    const int ridx = gidx % NRAY1;
    const int b    = gidx / NRAY1;
    float srcx, srcy, dx, dy, dz;
    int k0, k1;
    ray_setup(ridx, srcx, srcy, dx, dy, dz, k0, k1);

    const float stepf = (float)1.7320508075688773;
    const float t0f   = (float)416.8615612366939;

    const float* __restrict__ volb = vol + (size_t)b * NVOX;

    float acc = 0.0f;
    for (int k = k0; k <= k1; ++k) {
        const float tk = t0f + ((float)k + 0.5f) * stepf;
        const float ix = (srcx + dx * tk) + 47.5f;
        const float iy = (srcy + dy * tk) + 47.5f;
        const float iz = (dz * tk) + 47.5f;
        if (ix >= 0.0f && ix <= 95.0f &&
            iy >= 0.0f && iy <= 95.0f &&
            iz >= 0.0f && iz <= 95.0f) {
            const int x0 = min((int)ix, NXg - 2);
            const int y0 = min((int)iy, NYg - 2);
            const int z0 = min((int)iz, NZg - 2);
            const float fx = ix - (float)x0;
            const float fy = iy - (float)y0;
            const float fz = iz - (float)z0;
            const float* p = volb + ((z0 * NYg + y0) * NXg + x0);
            const float v000 = p[0];
            const float v001 = p[1];
            const float v010 = p[NXg];
            const float v011 = p[NXg + 1];
            const float v100 = p[NYg * NXg];
            const float v101 = p[NYg * NXg + 1];
            const float v110 = p[NYg * NXg + NXg];
            const float v111 = p[NYg * NXg + NXg + 1];
            const float c00 = v000 + fx * (v001 - v000);
            const float c01 = v010 + fx * (v011 - v010);
            const float c10 = v100 + fx * (v101 - v100);
            const float c11 = v110 + fx * (v111 - v110);
            const float c0  = c00 + fy * (c01 - c00);
            const float c1  = c10 + fy * (c11 - c10);
            acc += c0 + fz * (c1 - c0);
        }
    }
    out[gidx] = acc * stepf;
}

extern "C" void kernel_launch(void* const* d_in, const int* in_sizes, int n_in,
                              void* d_out, int out_size, void* d_ws, size_t ws_size,
                              hipStream_t stream) {
    const float* vol = (const float*)d_in[0];
    float* out = (float*)d_out;
    const size_t needed = (size_t)NVOX * sizeof(float2);  // ~7.08 MB
    if (ws_size >= needed) {
        float2* q = (float2*)d_ws;
        pack_b2<<<NVOX / 256, 256, 0, stream>>>(vol, q);
        coneproj_ksplit<<<(2 * NRAY1) / 256, 256, 0, stream>>>(q, out);
    } else {
        coneproj_direct<<<(NBg * NRAY1) / 256, 256, 0, stream>>>(vol, out);
    }
}

// Round 13
// 213.948 us; speedup vs baseline: 1.0499x; 1.0183x over previous
//
#include <hip/hip_runtime.h>
#include <math.h>

// Cone-beam forward projection (TIGRE Ax analogue).
// Volume: [B=2, NZ=96, NY=96, NX=96] f32, ZYX layout (x fastest).
// Output: [B=2, A=48, NV=96, NU=96] f32.
//
// FINAL (= R10, best of R2..R12): batch-interleaved float2 volume (7.1 MB,
// L2-resident), one thread per ray serving BOTH batches, 4 global_load_
// dwordx4 gathers per sample-pair.
//
// Cost model (validated by falsification rounds R5/R8/R9/R10/R11/R12):
// scattered-gather throughput ~17 B/cy/CU with ~30 cy/inst floor. This
// kernel moves the minimum needed bytes (16 floats/sample-pair = 4 KB per
// wave-iter -> ~241 cy/iter, measured 244) => gather-throughput roofline.
// Neutral/negative levers: fewer insts (R10), fewer lines/inst (R9), lane
// pairing (R5), dual layout (R8: L2 thrash), SW pipeline (R11: compiler
// re-serializes), 2x TLP (R12).
//
// CORRECTNESS-CRITICAL: reference integrand is DISCONTINUOUS at cube faces.
// Position path replicates the reference's f32 op sequence exactly:
// contract(off), per-sample src + d*t, IEEE sqrt+div, f64-rounded trig.
// absmax = 1.500 vs threshold 1.51 -> do not touch position arithmetic or
// reduce data precision.

#define NZg 96
#define NYg 96
#define NXg 96
#define NVg 96
#define NUg 96
#define NAg 48
#define NSg 96
#define NBg 2
#define NVOX (NZg * NYg * NXg)          // 884736 voxels per batch
#define NRAY1 (NAg * NVg * NUg)         // 442368 rays per batch
#define PLANE (NYg * NXg)               // 9216 float2 elements per z-plane

typedef float v4f __attribute__((ext_vector_type(4)));

// ---------------- staging: interleave the two batches ---------------------
__global__ __launch_bounds__(256) void pack_b2(
    const float* __restrict__ vol, float2* __restrict__ q) {
    const int i = blockIdx.x * blockDim.x + threadIdx.x;  // [z][y][x]
    float2 p;
    p.x = vol[i];
    p.y = vol[i + NVOX];
    q[i] = p;
}

// ---------------- shared geometry (b-independent) -------------------------
__device__ __forceinline__ void ray_setup(
    int ridx, float& srcx, float& srcy, float& dx, float& dy, float& dz,
    int& k0, int& k1) {
#pragma clang fp contract(off)
    const int u   = ridx % NUg;
    int tmp       = ridx / NUg;
    const int v   = tmp % NVg;
    const int a   = tmp / NVg;          // < 48, uniform per block

    // theta = a * (f32(2*pi) / 48)   [jax linspace f32 semantics]
    const float dtheta = 6.2831855f / 48.0f;
    const float theta  = (float)a * dtheta;
    const float c = (float)cos((double)theta);
    const float s = (float)sin((double)theta);

    srcx = 500.0f * c;
    srcy = 500.0f * s;
    const float uu = ((float)u - 47.5f) * 2.0f;
    const float vv = ((float)v - 47.5f) * 2.0f;
    const float pixx = (-500.0f * c) + uu * (-s);
    const float pixy = (-500.0f * s) + uu * c;
    const float pixz = vv;

    const float dx0 = pixx - srcx;
    const float dy0 = pixy - srcy;
    const float dz0 = pixz;
    const float nrm = sqrtf((dx0 * dx0 + dy0 * dy0) + dz0 * dz0);
    dx = dx0 / nrm;
    dy = dy0 / nrm;
    dz = dz0 / nrm;

    const float stepf = (float)1.7320508075688773;   // f32(2R/96)
    const float t0f   = (float)416.8615612366939;    // f32(DSO-R)

    // conservative AABB clip (skip-only; in-loop test is authoritative)
    const float LO = -47.51f, HI = 47.51f;
    float tlo = -1e30f, thi = 1e30f;
    {
        const float o3[3] = {srcx, srcy, 0.0f};
        const float d3[3] = {dx, dy, dz};
        bool empty = false;
        #pragma unroll
        for (int ax = 0; ax < 3; ++ax) {
            const float oo = o3[ax], dd = d3[ax];
            if (fabsf(dd) > 1e-8f) {
                const float inv = 1.0f / dd;
                const float ta = (LO - oo) * inv;
                const float tb = (HI - oo) * inv;
                tlo = fmaxf(tlo, fminf(ta, tb));
                thi = fminf(thi, fmaxf(ta, tb));
            } else if (oo < LO || oo > HI) {
                empty = true;
            }
        }
        if (empty) { tlo = 1.0f; thi = 0.0f; }
    }
    if (thi >= tlo) {
        k0 = (int)floorf((tlo - t0f) / stepf) - 2;
        k1 = (int)ceilf((thi - t0f) / stepf) + 2;
        k0 = max(k0, 0);
        k1 = min(k1, NSg - 1);
    } else {
        k0 = 1; k1 = 0;
    }
}

// ---------------- main: both batches per thread, x4 gathers ---------------
__global__ __launch_bounds__(256) void coneproj_b2x4(
    const float2* __restrict__ q, float* __restrict__ out) {
#pragma clang fp contract(off)
    const int ridx = blockIdx.x * blockDim.x + threadIdx.x;  // (a*96+v)*96+u
    float srcx, srcy, dx, dy, dz;
    int k0, k1;
    ray_setup(ridx, srcx, srcy, dx, dy, dz, k0, k1);

    const float stepf = (float)1.7320508075688773;
    const float t0f   = (float)416.8615612366939;

    float acc0 = 0.0f, acc1 = 0.0f;
    for (int k = k0; k <= k1; ++k) {
        const float tk = t0f + ((float)k + 0.5f) * stepf;
        const float ix = (srcx + dx * tk) + 47.5f;
        const float iy = (srcy + dy * tk) + 47.5f;
        const float iz = (dz * tk) + 47.5f;
        if (ix >= 0.0f && ix <= 95.0f &&
            iy >= 0.0f && iy <= 95.0f &&
            iz >= 0.0f && iz <= 95.0f) {
            const int x0 = min((int)ix, NXg - 2);
            const int y0 = min((int)iy, NYg - 2);
            const int z0 = min((int)iz, NZg - 2);
            const float fx = ix - (float)x0;
            const float fy = iy - (float)y0;
            const float fz = iz - (float)z0;
            const int base = (z0 * NYg + y0) * NXg + x0;
            // 4 x 16B gathers at 8B-aligned addresses: each row-load gives
            // (b0@x0, b1@x0, b0@x1, b1@x1) for one (y,z) corner row.
            const v4f r00 = *(const v4f*)(q + base);                // (y0,z0)
            const v4f r01 = *(const v4f*)(q + base + NXg);          // (y1,z0)
            const v4f r10 = *(const v4f*)(q + base + PLANE);        // (y0,z1)
            const v4f r11 = *(const v4f*)(q + base + PLANE + NXg);  // (y1,z1)
            // batch 0 (op-order identical to R2/R7): .x = b0@x0, .z = b0@x1
            {
                const float c00 = r00.x + fx * (r00.z - r00.x);
                const float c01 = r01.x + fx * (r01.z - r01.x);
                const float c10 = r10.x + fx * (r10.z - r10.x);
                const float c11 = r11.x + fx * (r11.z - r11.x);
                const float c0  = c00 + fy * (c01 - c00);
                const float c1  = c10 + fy * (c11 - c10);
                acc0 += c0 + fz * (c1 - c0);
            }
            // batch 1: .y = b1@x0, .w = b1@x1
            {
                const float c00 = r00.y + fx * (r00.w - r00.y);
                const float c01 = r01.y + fx * (r01.w - r01.y);
                const float c10 = r10.y + fx * (r10.w - r10.y);
                const float c11 = r11.y + fx * (r11.w - r11.y);
                const float c0  = c00 + fy * (c01 - c00);
                const float c1  = c10 + fy * (c11 - c10);
                acc1 += c0 + fz * (c1 - c0);
            }
        }
    }
    out[ridx]         = acc0 * stepf;
    out[ridx + NRAY1] = acc1 * stepf;
}

// ---------------- fallback: direct 8-gather projector (R2) ----------------
__global__ __launch_bounds__(256) void coneproj_direct(
    const float* __restrict__ vol, float* __restrict__ out) {
#pragma clang fp contract(off)
    const int gidx = blockIdx.x * blockDim.x + threadIdx.x;  // includes b
    const int ridx = gidx % NRAY1;
    const int b    = gidx / NRAY1;
    float srcx, srcy, dx, dy, dz;
    int k0, k1;
    ray_setup(ridx, srcx, srcy, dx, dy, dz, k0, k1);

    const float stepf = (float)1.7320508075688773;
    const float t0f   = (float)416.8615612366939;

    const float* __restrict__ volb = vol + (size_t)b * NVOX;

    float acc = 0.0f;
    for (int k = k0; k <= k1; ++k) {
        const float tk = t0f + ((float)k + 0.5f) * stepf;
        const float ix = (srcx + dx * tk) + 47.5f;
        const float iy = (srcy + dy * tk) + 47.5f;
        const float iz = (dz * tk) + 47.5f;
        if (ix >= 0.0f && ix <= 95.0f &&
            iy >= 0.0f && iy <= 95.0f &&
            iz >= 0.0f && iz <= 95.0f) {
            const int x0 = min((int)ix, NXg - 2);
            const int y0 = min((int)iy, NYg - 2);
            const int z0 = min((int)iz, NZg - 2);
            const float fx = ix - (float)x0;
            const float fy = iy - (float)y0;
            const float fz = iz - (float)z0;
            const float* p = volb + ((z0 * NYg + y0) * NXg + x0);
            const float v000 = p[0];
            const float v001 = p[1];
            const float v010 = p[NXg];
            const float v011 = p[NXg + 1];
            const float v100 = p[NYg * NXg];
            const float v101 = p[NYg * NXg + 1];
            const float v110 = p[NYg * NXg + NXg];
            const float v111 = p[NYg * NXg + NXg + 1];
            const float c00 = v000 + fx * (v001 - v000);
            const float c01 = v010 + fx * (v011 - v010);
            const float c10 = v100 + fx * (v101 - v100);
            const float c11 = v110 + fx * (v111 - v110);
            const float c0  = c00 + fy * (c01 - c00);
            const float c1  = c10 + fy * (c11 - c10);
            acc += c0 + fz * (c1 - c0);
        }
    }
    out[gidx] = acc * stepf;
}

extern "C" void kernel_launch(void* const* d_in, const int* in_sizes, int n_in,
                              void* d_out, int out_size, void* d_ws, size_t ws_size,
                              hipStream_t stream) {
    const float* vol = (const float*)d_in[0];
    float* out = (float*)d_out;
    const size_t needed = (size_t)NVOX * sizeof(float2);  // ~7.08 MB
    if (ws_size >= needed) {
        float2* q = (float2*)d_ws;
        pack_b2<<<NVOX / 256, 256, 0, stream>>>(vol, q);
        coneproj_b2x4<<<NRAY1 / 256, 256, 0, stream>>>(q, out);
    } else {
        coneproj_direct<<<(NBg * NRAY1) / 256, 256, 0, stream>>>(vol, out);
    }
}